// Round 4
// baseline (67.593 us; speedup 1.0000x reference)
//
#include <hip/hip_runtime.h>
#include <hip/hip_bf16.h>

// QGenModel self_diff_attention, algebraically factored (exact, fp32):
//   logits[b,n,g] = sum_d obj[b,n,d]^2 * S[g,d] - obj[b,n,d] * T[b,g,d] + bias[g]
//     S[g,d]   = sum_m W[g,m,d]
//     T[b,g,d] = sum_m W[g,m,d] * obj[b,m,d]
// masked softmax over n, then vis[b,g,d] = sum_n w[b,n,g]*obj[b,n,d].
//
// Round-4: fully float4-vectorized; obj kept in registers (float4 o4[9] per
// thread, 4 m-groups x 9 rows); no pass-2 global re-read. Per-block global
// traffic = obj(73.7KB) + W(73.7KB) once — the structural floor.
// Grid = 256 = one block per (batch, glimpse); b = bid&127, g = bid>>7 puts
// both glimpse-blocks of a batch on the same XCD (128 % 8 == 0).

#define QB 128
#define QN 36
#define QD 512
#define QG 2
#define NROW 9   // rows per m-group (QN / 4)

__global__ __launch_bounds__(512) void qgen_self_diff_attn(
    const float* __restrict__ obj,   // [B, N, D]
    const float* __restrict__ W,     // [G, N*D]
    const float* __restrict__ bias,  // [G]
    const int* __restrict__ mask,    // [B, N] (0/1)
    float* __restrict__ out)         // [B, G*D]
{
    __shared__ float4 s_p4[4][128];  // 8 KiB: T partials, later vis partials
    __shared__ float4 s_q4[4][128];  // 8 KiB: S partials
    __shared__ float s_T[QD];        // 2 KiB reduced T
    __shared__ float s_S[QD];        // 2 KiB reduced S
    __shared__ float s_pp[8][NROW];  // per-wave logit partials
    __shared__ float s_logit[QN];
    __shared__ float s_w[QN];

    const int bid = blockIdx.x;
    const int b = bid & (QB - 1);    // batch
    const int g = bid >> 7;          // glimpse
    const int t = threadIdx.x;       // 0..511
    const int w = t >> 6;            // wave 0..7
    const int lane = t & 63;
    const int mq = t >> 7;           // m-group 0..3
    const int dq = t & 127;          // float4 column 0..127

    const float4* ob4 = (const float4*)(obj + (size_t)b * QN * QD);
    const float4* wg4 = (const float4*)(W + (size_t)g * QN * QD);

    // ---- Pass 1: load obj rows (mq, mq+4, ...) as float4; T/S partials ----
    float4 o4[NROW];
    float4 T4 = make_float4(0.f, 0.f, 0.f, 0.f);
    float4 S4 = make_float4(0.f, 0.f, 0.f, 0.f);
    #pragma unroll
    for (int i = 0; i < NROW; ++i) {
        int m = mq + 4 * i;
        float4 o = ob4[m * 128 + dq];
        float4 wv = wg4[m * 128 + dq];
        o4[i] = o;
        T4.x = fmaf(wv.x, o.x, T4.x);  T4.y = fmaf(wv.y, o.y, T4.y);
        T4.z = fmaf(wv.z, o.z, T4.z);  T4.w = fmaf(wv.w, o.w, T4.w);
        S4.x += wv.x;  S4.y += wv.y;  S4.z += wv.z;  S4.w += wv.w;
    }
    s_p4[mq][dq] = T4;
    s_q4[mq][dq] = S4;
    __syncthreads();

    // ---- Reduce T/S over the 4 m-groups; thread t owns d = t ----
    {
        const float* fT = (const float*)s_p4;
        const float* fS = (const float*)s_q4;
        s_T[t] = fT[0 * QD + t] + fT[1 * QD + t] + fT[2 * QD + t] + fT[3 * QD + t];
        s_S[t] = fS[0 * QD + t] + fS[1 * QD + t] + fS[2 * QD + t] + fS[3 * QD + t];
    }
    __syncthreads();

    // ---- Pass 2: logits from registers. Group mq owns n = mq + 4*i ----
    {
        float4 ST = ((const float4*)s_T)[dq];
        float4 SS = ((const float4*)s_S)[dq];
        #pragma unroll
        for (int i = 0; i < NROW; ++i) {
            float4 o = o4[i];
            float a = (o.x * o.x) * SS.x - o.x * ST.x
                    + (o.y * o.y) * SS.y - o.y * ST.y
                    + (o.z * o.z) * SS.z - o.z * ST.z
                    + (o.w * o.w) * SS.w - o.w * ST.w;
            #pragma unroll
            for (int off = 32; off; off >>= 1)
                a += __shfl_down(a, off);
            if (lane == 0) s_pp[w][i] = a;
        }
    }
    __syncthreads();

    // combine the two waves of each group; apply mask + bias
    if (t < QN) {
        int n = t;
        int nmq = n & 3, ni = n >> 2;
        float a = s_pp[2 * nmq][ni] + s_pp[2 * nmq + 1][ni];
        bool mk = mask[b * QN + n] != 0;
        s_logit[n] = mk ? a + bias[g] : -1e10f;
    }
    __syncthreads();

    // ---- Pass 3: masked softmax over n, wave 0 only ----
    if (w == 0) {
        float v = (lane < QN) ? s_logit[lane] : -1e30f;
        float mx = v;
        #pragma unroll
        for (int off = 32; off; off >>= 1)
            mx = fmaxf(mx, __shfl_xor(mx, off));
        float e = (lane < QN) ? __expf(v - mx) : 0.f;
        float sum = e;
        #pragma unroll
        for (int off = 32; off; off >>= 1)
            sum += __shfl_xor(sum, off);
        if (lane < QN) s_w[lane] = e / sum;
    }
    __syncthreads();

    // ---- Pass 4: vis partials from registers, reduce over m-groups ----
    {
        float4 v4 = make_float4(0.f, 0.f, 0.f, 0.f);
        #pragma unroll
        for (int i = 0; i < NROW; ++i) {
            float wn = s_w[mq + 4 * i];   // wave-uniform broadcast
            v4.x = fmaf(wn, o4[i].x, v4.x);
            v4.y = fmaf(wn, o4[i].y, v4.y);
            v4.z = fmaf(wn, o4[i].z, v4.z);
            v4.w = fmaf(wn, o4[i].w, v4.w);
        }
        s_p4[mq][dq] = v4;   // reuse T-partial buffer
    }
    __syncthreads();

    if (t < 128) {
        float4 a = s_p4[0][t], b4 = s_p4[1][t], c = s_p4[2][t], d = s_p4[3][t];
        float4 r;
        r.x = a.x + b4.x + c.x + d.x;
        r.y = a.y + b4.y + c.y + d.y;
        r.z = a.z + b4.z + c.z + d.z;
        r.w = a.w + b4.w + c.w + d.w;
        ((float4*)out)[(size_t)b * (QG * QD / 4) + g * (QD / 4) + t] = r;
    }
}

extern "C" void kernel_launch(void* const* d_in, const int* in_sizes, int n_in,
                              void* d_out, int out_size, void* d_ws, size_t ws_size,
                              hipStream_t stream) {
    const float* obj  = (const float*)d_in[0];
    const float* W    = (const float*)d_in[1];
    const float* bias = (const float*)d_in[2];
    const int*   mask = (const int*)d_in[3];
    float* out = (float*)d_out;

    qgen_self_diff_attn<<<QB * QG, 512, 0, stream>>>(obj, W, bias, mask, out);
}